// Round 17
// baseline (274.603 us; speedup 1.0000x reference)
//
#include <hip/hip_runtime.h>
#include <hip/hip_bf16.h>
#include <stdint.h>

// Problem constants
#define M_REAL 36928LL      // 64*577
#define M_PAD  36992LL      // 289*128
#define DDIM   1024
#define SSEQ   577
#define NBATCH 64

typedef __attribute__((ext_vector_type(8))) short bf16x8;
typedef __attribute__((ext_vector_type(4))) float f32x4;

// ws layout (bytes)
#define XBF_OFF   0ULL                  // 36992*1024*2 = 75,759,616
#define WBF_OFF   75759616ULL           // 1024*1024*2  =  2,097,152
#define ABF_OFF   77856768ULL           // 8*16*1024*2  =    262,144
#define XABF_OFF  78118912ULL           // 36992*32*2   =  2,367,488
#define GBBF_OFF  80486400ULL           // 64*1024*32*2 =  4,194,304
#define WS_NEED   84680704ULL

__device__ __forceinline__ unsigned short f2bf(float f) {
  union { float f; unsigned int u; } v; v.f = f;
  unsigned int u = v.u;
  unsigned int r = (u + 0x7fffu + ((u >> 16) & 1u)) >> 16;  // RNE
  return (unsigned short)r;
}

__device__ __forceinline__ bf16x8 cvt8(const float* __restrict__ p) {
  float4 a = *(const float4*)p;
  float4 b = *(const float4*)(p + 4);
  bf16x8 o;
  o[0] = (short)f2bf(a.x); o[1] = (short)f2bf(a.y);
  o[2] = (short)f2bf(a.z); o[3] = (short)f2bf(a.w);
  o[4] = (short)f2bf(b.x); o[5] = (short)f2bf(b.y);
  o[6] = (short)f2bf(b.z); o[7] = (short)f2bf(b.w);
  return o;
}

#define GLOAD_LDS16(gsrc, ldst)                                                  \
  __builtin_amdgcn_global_load_lds((const __attribute__((address_space(1))) void*)(gsrc), \
                                   (__attribute__((address_space(3))) void*)(ldst), 16, 0, 0)

// ---------------- kernel 1: prep (cast W, cast A, build gB, zero pads) ------
// r13 version (measured best front-end).
__global__ void prep_kernel(const float* __restrict__ W,
                            const float* __restrict__ A_all,
                            const float* __restrict__ B_all,
                            const int* __restrict__ idx,
                            const float* __restrict__ gates,
                            unsigned short* __restrict__ wbf,
                            unsigned short* __restrict__ abf,
                            unsigned short* __restrict__ gbbf,
                            unsigned short* __restrict__ xbf,
                            unsigned short* __restrict__ xabf) {
  const int W_UNITS = 131072;                 // 8 elems each (1M total)
  const int A_UNITS = 16384;                  // 8 elems each (131072 total)
  const int G_UNITS = 65536;                  // one (b,n) row of 32 each
  const int XP_UNITS = 8192;                  // xbf pad rows (64 rows * 1024 / 8)
  const int P_UNITS = 2048;                   // xa pad elems (64 rows * 32)
  const int TOTAL = W_UNITS + A_UNITS + G_UNITS + XP_UNITS + P_UNITS; // 223232
  int u = blockIdx.x * blockDim.x + threadIdx.x;
  int stride = gridDim.x * blockDim.x;
  for (; u < TOTAL; u += stride) {
    if (u < W_UNITS) {
      int i = u * 8;
      *(bf16x8*)(wbf + i) = cvt8(W + i);
    } else if (u < W_UNITS + A_UNITS) {
      int i = (u - W_UNITS) * 8;
      *(bf16x8*)(abf + i) = cvt8(A_all + i);
    } else if (u < W_UNITS + A_UNITS + G_UNITS) {
      int v = u - W_UNITS - A_UNITS;
      int b = v >> 10;
      int n = v & 1023;
      unsigned short tmp[32];
#pragma unroll
      for (int k = 0; k < 2; ++k) {
        int e = idx[b * 2 + k];
        float g = gates[b * 2 + k];
        const float* Br = B_all + ((size_t)e * 1024 + n) * 16;
#pragma unroll
        for (int r = 0; r < 16; ++r) tmp[k * 16 + r] = f2bf(g * Br[r]);
      }
      unsigned short* dst = gbbf + (size_t)v * 32;
#pragma unroll
      for (int j = 0; j < 32; ++j) dst[j] = tmp[j];
    } else if (u < W_UNITS + A_UNITS + G_UNITS + XP_UNITS) {
      int v = u - W_UNITS - A_UNITS - G_UNITS;
      bf16x8 z;
#pragma unroll
      for (int j = 0; j < 8; ++j) z[j] = 0;
      *(bf16x8*)(xbf + (size_t)M_REAL * DDIM + (size_t)v * 8) = z;
    } else {
      int v = u - W_UNITS - A_UNITS - G_UNITS - XP_UNITS;
      xabf[(size_t)M_REAL * 32 + v] = 0;
    }
  }
}

// ---------------- kernel 2: fused cast x->bf16 + xa = x @ A_sel^T -----------
// r13 version: ~6.6 TB/s (HBM roofline).
__global__ __launch_bounds__(256) void cast_xa_kernel(
    const float* __restrict__ x,
    const unsigned short* __restrict__ abf,
    const int* __restrict__ idx,
    unsigned short* __restrict__ xbf,
    unsigned short* __restrict__ xabf) {
  int bid = blockIdx.x;
  int b = bid / 10;
  int s0 = (bid % 10) * 64;
  int wave = threadIdx.x >> 6;
  int lane = threadIdx.x & 63;
  int l15 = lane & 15, lhi = lane >> 4;

  int srow = s0 + wave * 16 + l15;
  bool valid = srow < SSEQ;
  long long mrow = (long long)b * SSEQ + (valid ? srow : 0);
  const float* xrow = x + (size_t)mrow * DDIM;
  unsigned short* xbrow = xbf + (size_t)mrow * DDIM;
  int e0 = idx[b * 2 + 0], e1 = idx[b * 2 + 1];
  const unsigned short* ar0 = abf + ((size_t)e0 * 16 + l15) * DDIM;
  const unsigned short* ar1 = abf + ((size_t)e1 * 16 + l15) * DDIM;

  f32x4 acc0 = {0.f, 0.f, 0.f, 0.f}, acc1 = {0.f, 0.f, 0.f, 0.f};
  for (int k = 0; k < DDIM; k += 32) {
    int ko = k + lhi * 8;
    bf16x8 a;
    if (valid) {
      a = cvt8(xrow + ko);
      *(bf16x8*)(xbrow + ko) = a;
    } else {
#pragma unroll
      for (int j = 0; j < 8; ++j) a[j] = 0;
    }
    bf16x8 b0 = *(const bf16x8*)(ar0 + ko);
    bf16x8 b1 = *(const bf16x8*)(ar1 + ko);
    acc0 = __builtin_amdgcn_mfma_f32_16x16x32_bf16(a, b0, acc0, 0, 0, 0);
    acc1 = __builtin_amdgcn_mfma_f32_16x16x32_bf16(a, b1, acc1, 0, 0, 0);
  }
  // C layout: col = lane&15 (=r), row = (lane>>4)*4+reg
  int sout = s0 + wave * 16 + lhi * 4;
#pragma unroll
  for (int reg = 0; reg < 4; ++reg) {
    int s = sout + reg;
    if (s < SSEQ) {
      size_t mo = ((size_t)b * SSEQ + s) * 32;
      xabf[mo + l15]      = f2bf(acc0[reg]);
      xabf[mo + 16 + l15] = f2bf(acc1[reg]);
    }
  }
}

// ---------------- kernel 3: 128x64 GEMM, B direct from L2 -------------------
// C[m,n] = sum_d x[m,d]*W[n,d] + bias[n] + sum_kr xa[m,kr]*gB[b(m),n,kr]
// r16 base (131us, LDS pipe 58% = top-utilized) + B-fragments read straight
// from wbf (2MB, L2-resident) instead of LDS staging: LDS bytes -33%,
// B bytes move to the underused L2 pipe. A path/LoRA/epilogue unchanged.
#define BM 128
#define BN 64
#define BKT 64
__global__ __launch_bounds__(256, 5) void gemm_kernel(
    const unsigned short* __restrict__ xbf,
    const unsigned short* __restrict__ wbf,
    const unsigned short* __restrict__ xabf,
    const unsigned short* __restrict__ gbbf,
    const float* __restrict__ bias,
    float* __restrict__ out) {
  __shared__ unsigned short As[BM * BKT];   // 16 KiB (also epilogue scratch)

  // XCD-chunked bijective swizzle: 4624 blocks = 8 XCDs x 578
  int g = blockIdx.x;
  int xcd = g & 7, gi = g >> 3;
  int wg = xcd * 578 + gi;
  const int bm = wg >> 4;              // 0..288
  const int bn = wg & 15;              // 0..15
  const long long m0 = (long long)bm * BM;
  const int n0 = bn * BN;

  const int tid = threadIdx.x;
  const int wave = tid >> 6, lane = tid & 63;
  const int l15 = lane & 15, lhi = lane >> 4;
  const int wm = (wave >> 1) * 64;     // 0,64
  const int wn2 = (wave & 1) * 32;     // 0,32

  f32x4 acc[4][2];
#pragma unroll
  for (int i = 0; i < 4; ++i)
#pragma unroll
    for (int j = 0; j < 2; ++j) acc[i][j] = (f32x4){0.f, 0.f, 0.f, 0.f};

  // A staging: rows wave*32+i*8+(lane>>3) (4 gloads)
  // swizzle: LDS[row][q] = global[row][q ^ (row&7)]; row&7 = lane>>3
  const int rowbase = wave * 32;
  const int rl = lane >> 3;
  const int csrc = (((lane & 7) ^ rl) << 3);   // elems

  // A frag reads: desired chunk q = ks*4+lhi -> LDS chunk q ^ (l15&7)
  const int sl0 = ((lhi ^ (l15 & 7)) << 3);
  const int sl1 = sl0 ^ 32;

  // B frag reads: straight from global (L2-hot W panel), no swizzle needed
  const unsigned short* bp = wbf + (size_t)(n0 + wn2 + l15) * DDIM + lhi * 8;

  for (int k0 = 0; k0 < DDIM; k0 += BKT) {
#pragma unroll
    for (int i = 0; i < 4; ++i) {
      int r = rowbase + i * 8;
      GLOAD_LDS16(xbf + (size_t)(m0 + r + rl) * DDIM + k0 + csrc, &As[r * BKT]);
    }
    // B fragments from L2 while A staging is in flight
    bf16x8 bfv[2][2];
#pragma unroll
    for (int nf = 0; nf < 2; ++nf) {
      bfv[nf][0] = *(const bf16x8*)(bp + (size_t)nf * 16 * DDIM + k0);
      bfv[nf][1] = *(const bf16x8*)(bp + (size_t)nf * 16 * DDIM + k0 + 32);
    }
    __syncthreads();
    {
      bf16x8 af[4][2];
#pragma unroll
      for (int f = 0; f < 4; ++f) {
        af[f][0] = *(const bf16x8*)&As[(wm + f * 16 + l15) * BKT + sl0];
        af[f][1] = *(const bf16x8*)&As[(wm + f * 16 + l15) * BKT + sl1];
      }
#pragma unroll
      for (int f = 0; f < 4; ++f)
#pragma unroll
        for (int nf = 0; nf < 2; ++nf)
#pragma unroll
          for (int ks = 0; ks < 2; ++ks)
            acc[f][nf] = __builtin_amdgcn_mfma_f32_16x16x32_bf16(
                af[f][ks], bfv[nf][ks], acc[f][nf], 0, 0, 0);
    }
    __syncthreads();
  }

  // LoRA rank-32 extra K-steps, masked per batch (128-row tile spans <= 2)
  long long mlast = m0 + BM - 1; if (mlast > M_REAL - 1) mlast = M_REAL - 1;
  int b_lo = (int)(m0 / SSEQ);
  int b_hi = (int)(mlast / SSEQ);
  for (int bs = b_lo; bs <= b_hi; ++bs) {
    bf16x8 gb[2];
#pragma unroll
    for (int nf = 0; nf < 2; ++nf) {
      int n = n0 + wn2 + nf * 16 + l15;
      gb[nf] = *(const bf16x8*)&gbbf[((size_t)bs * 1024 + n) * 32 + lhi * 8];
    }
#pragma unroll
    for (int f = 0; f < 4; ++f) {
      long long m = m0 + wm + f * 16 + l15;
      bf16x8 v = *(const bf16x8*)&xabf[(size_t)m * 32 + lhi * 8];  // pad rows zero
      if ((int)(m / SSEQ) != bs) {
#pragma unroll
        for (int j = 0; j < 8; ++j) v[j] = 0;
      }
#pragma unroll
      for (int nf = 0; nf < 2; ++nf)
        acc[f][nf] = __builtin_amdgcn_mfma_f32_16x16x32_bf16(v, gb[nf], acc[f][nf], 0, 0, 0);
    }
  }

  // epilogue: + bias; per-wave LDS transpose (16x32 f32, stride 36); NT stores.
  {
    float* lfs = (float*)As + wave * 640;    // 16*36=576 used, 640 spacing
    const long long mrow0 = m0 + wm;
    const int ncol0 = n0 + wn2;
#pragma unroll
    for (int i = 0; i < 4; ++i) {
#pragma unroll
      for (int j = 0; j < 2; ++j) {
        float bv = bias[ncol0 + j * 16 + l15];
#pragma unroll
        for (int reg = 0; reg < 4; ++reg)
          lfs[(lhi * 4 + reg) * 36 + j * 16 + l15] = acc[i][j][reg] + bv;
      }
      // in-wave LDS ordering: compiler inserts lgkmcnt before dependent reads
#pragma unroll
      for (int rr = 0; rr < 2; ++rr) {
        int r16 = rr * 8 + (lane >> 3);
        f32x4 v = *(const f32x4*)&lfs[r16 * 36 + (lane & 7) * 4];
        long long m = mrow0 + i * 16 + r16;
        if (m < M_REAL)
          __builtin_nontemporal_store(v, (f32x4*)&out[m * DDIM + ncol0 + (lane & 7) * 4]);
      }
    }
  }
}

extern "C" void kernel_launch(void* const* d_in, const int* in_sizes, int n_in,
                              void* d_out, int out_size, void* d_ws, size_t ws_size,
                              hipStream_t stream) {
  const float* x      = (const float*)d_in[0];
  const int*   idx    = (const int*)d_in[1];
  const float* gates  = (const float*)d_in[2];
  const float* W      = (const float*)d_in[3];
  const float* A_all  = (const float*)d_in[4];
  const float* B_all  = (const float*)d_in[5];
  const float* bias   = (const float*)d_in[6];
  float* out = (float*)d_out;

  char* ws = (char*)d_ws;
  unsigned short* xbf  = (unsigned short*)(ws + XBF_OFF);
  unsigned short* wbf  = (unsigned short*)(ws + WBF_OFF);
  unsigned short* abf  = (unsigned short*)(ws + ABF_OFF);
  unsigned short* xabf = (unsigned short*)(ws + XABF_OFF);
  unsigned short* gbbf = (unsigned short*)(ws + GBBF_OFF);

  prep_kernel<<<dim3(872), dim3(256), 0, stream>>>(W, A_all, B_all, idx, gates,
                                                   wbf, abf, gbbf, xbf, xabf);
  cast_xa_kernel<<<dim3(640), dim3(256), 0, stream>>>(x, abf, idx, xbf, xabf);
  gemm_kernel<<<dim3(4624), dim3(256), 0, stream>>>(xbf, wbf, xabf, gbbf, bias, out);
}

// Round 18
// 159.978 us; speedup vs baseline: 1.7165x; 1.7165x over previous
//
#include <hip/hip_runtime.h>
#include <hip/hip_bf16.h>
#include <stdint.h>

// Problem constants
#define M_REAL 36928LL      // 64*577
#define M_PAD  36992LL      // 289*128
#define DDIM   1024
#define SSEQ   577
#define NBATCH 64

typedef __attribute__((ext_vector_type(8))) short bf16x8;
typedef __attribute__((ext_vector_type(4))) float f32x4;

// ws layout (bytes)
#define XBF_OFF   0ULL                  // 36992*1024*2 = 75,759,616
#define WBF_OFF   75759616ULL           // 1024*1024*2  =  2,097,152
#define ABF_OFF   77856768ULL           // 8*16*1024*2  =    262,144
#define XABF_OFF  78118912ULL           // 36992*32*2   =  2,367,488
#define GBBF_OFF  80486400ULL           // 64*1024*32*2 =  4,194,304
#define WS_NEED   84680704ULL

__device__ __forceinline__ unsigned short f2bf(float f) {
  union { float f; unsigned int u; } v; v.f = f;
  unsigned int u = v.u;
  unsigned int r = (u + 0x7fffu + ((u >> 16) & 1u)) >> 16;  // RNE
  return (unsigned short)r;
}

__device__ __forceinline__ bf16x8 cvt8(const float* __restrict__ p) {
  float4 a = *(const float4*)p;
  float4 b = *(const float4*)(p + 4);
  bf16x8 o;
  o[0] = (short)f2bf(a.x); o[1] = (short)f2bf(a.y);
  o[2] = (short)f2bf(a.z); o[3] = (short)f2bf(a.w);
  o[4] = (short)f2bf(b.x); o[5] = (short)f2bf(b.y);
  o[6] = (short)f2bf(b.z); o[7] = (short)f2bf(b.w);
  return o;
}

#define GLOAD_LDS16(gsrc, ldst)                                                  \
  __builtin_amdgcn_global_load_lds((const __attribute__((address_space(1))) void*)(gsrc), \
                                   (__attribute__((address_space(3))) void*)(ldst), 16, 0, 0)

// ---------------- kernel 1: prep (cast W, cast A, build gB, zero pads) ------
// r13 version (measured best front-end).
__global__ void prep_kernel(const float* __restrict__ W,
                            const float* __restrict__ A_all,
                            const float* __restrict__ B_all,
                            const int* __restrict__ idx,
                            const float* __restrict__ gates,
                            unsigned short* __restrict__ wbf,
                            unsigned short* __restrict__ abf,
                            unsigned short* __restrict__ gbbf,
                            unsigned short* __restrict__ xbf,
                            unsigned short* __restrict__ xabf) {
  const int W_UNITS = 131072;                 // 8 elems each (1M total)
  const int A_UNITS = 16384;                  // 8 elems each (131072 total)
  const int G_UNITS = 65536;                  // one (b,n) row of 32 each
  const int XP_UNITS = 8192;                  // xbf pad rows (64 rows * 1024 / 8)
  const int P_UNITS = 2048;                   // xa pad elems (64 rows * 32)
  const int TOTAL = W_UNITS + A_UNITS + G_UNITS + XP_UNITS + P_UNITS; // 223232
  int u = blockIdx.x * blockDim.x + threadIdx.x;
  int stride = gridDim.x * blockDim.x;
  for (; u < TOTAL; u += stride) {
    if (u < W_UNITS) {
      int i = u * 8;
      *(bf16x8*)(wbf + i) = cvt8(W + i);
    } else if (u < W_UNITS + A_UNITS) {
      int i = (u - W_UNITS) * 8;
      *(bf16x8*)(abf + i) = cvt8(A_all + i);
    } else if (u < W_UNITS + A_UNITS + G_UNITS) {
      int v = u - W_UNITS - A_UNITS;
      int b = v >> 10;
      int n = v & 1023;
      unsigned short tmp[32];
#pragma unroll
      for (int k = 0; k < 2; ++k) {
        int e = idx[b * 2 + k];
        float g = gates[b * 2 + k];
        const float* Br = B_all + ((size_t)e * 1024 + n) * 16;
#pragma unroll
        for (int r = 0; r < 16; ++r) tmp[k * 16 + r] = f2bf(g * Br[r]);
      }
      unsigned short* dst = gbbf + (size_t)v * 32;
#pragma unroll
      for (int j = 0; j < 32; ++j) dst[j] = tmp[j];
    } else if (u < W_UNITS + A_UNITS + G_UNITS + XP_UNITS) {
      int v = u - W_UNITS - A_UNITS - G_UNITS;
      bf16x8 z;
#pragma unroll
      for (int j = 0; j < 8; ++j) z[j] = 0;
      *(bf16x8*)(xbf + (size_t)M_REAL * DDIM + (size_t)v * 8) = z;
    } else {
      int v = u - W_UNITS - A_UNITS - G_UNITS - XP_UNITS;
      xabf[(size_t)M_REAL * 32 + v] = 0;
    }
  }
}

// ---------------- kernel 2: fused cast x->bf16 + xa = x @ A_sel^T -----------
// r13 version: ~6.6 TB/s (HBM roofline).
__global__ __launch_bounds__(256) void cast_xa_kernel(
    const float* __restrict__ x,
    const unsigned short* __restrict__ abf,
    const int* __restrict__ idx,
    unsigned short* __restrict__ xbf,
    unsigned short* __restrict__ xabf) {
  int bid = blockIdx.x;
  int b = bid / 10;
  int s0 = (bid % 10) * 64;
  int wave = threadIdx.x >> 6;
  int lane = threadIdx.x & 63;
  int l15 = lane & 15, lhi = lane >> 4;

  int srow = s0 + wave * 16 + l15;
  bool valid = srow < SSEQ;
  long long mrow = (long long)b * SSEQ + (valid ? srow : 0);
  const float* xrow = x + (size_t)mrow * DDIM;
  unsigned short* xbrow = xbf + (size_t)mrow * DDIM;
  int e0 = idx[b * 2 + 0], e1 = idx[b * 2 + 1];
  const unsigned short* ar0 = abf + ((size_t)e0 * 16 + l15) * DDIM;
  const unsigned short* ar1 = abf + ((size_t)e1 * 16 + l15) * DDIM;

  f32x4 acc0 = {0.f, 0.f, 0.f, 0.f}, acc1 = {0.f, 0.f, 0.f, 0.f};
  for (int k = 0; k < DDIM; k += 32) {
    int ko = k + lhi * 8;
    bf16x8 a;
    if (valid) {
      a = cvt8(xrow + ko);
      *(bf16x8*)(xbrow + ko) = a;
    } else {
#pragma unroll
      for (int j = 0; j < 8; ++j) a[j] = 0;
    }
    bf16x8 b0 = *(const bf16x8*)(ar0 + ko);
    bf16x8 b1 = *(const bf16x8*)(ar1 + ko);
    acc0 = __builtin_amdgcn_mfma_f32_16x16x32_bf16(a, b0, acc0, 0, 0, 0);
    acc1 = __builtin_amdgcn_mfma_f32_16x16x32_bf16(a, b1, acc1, 0, 0, 0);
  }
  // C layout: col = lane&15 (=r), row = (lane>>4)*4+reg
  int sout = s0 + wave * 16 + lhi * 4;
#pragma unroll
  for (int reg = 0; reg < 4; ++reg) {
    int s = sout + reg;
    if (s < SSEQ) {
      size_t mo = ((size_t)b * SSEQ + s) * 32;
      xabf[mo + l15]      = f2bf(acc0[reg]);
      xabf[mo + 16 + l15] = f2bf(acc1[reg]);
    }
  }
}

// ---------------- kernel 3: 128x64 GEMM, LDS dbuf + counted vmcnt -----------
// C[m,n] = sum_d x[m,d]*W[n,d] + bias[n] + sum_kr xa[m,kr]*gB[b(m),n,kr]
// r16 tile/swizzles/epilogue + depth-1 LDS double-buffer with raw barriers:
// per tile {compute buf[p]; lgkm0; BAR; STAGE(t+2 -> buf[p]); vmcnt(6); BAR}.
// vmcnt(6) leaves exactly t+2's 6 loads in flight => t+1 landed (ledger).
// 48KB LDS -> 3 blocks/CU (pipeline + TLP together; 1-block pipelines failed).
#define BM 128
#define BN 64
#define BKT 64
__global__ __launch_bounds__(256, 3) void gemm_kernel(
    const unsigned short* __restrict__ xbf,
    const unsigned short* __restrict__ wbf,
    const unsigned short* __restrict__ xabf,
    const unsigned short* __restrict__ gbbf,
    const float* __restrict__ bias,
    float* __restrict__ out) {
  __shared__ unsigned short As0[8192], As1[8192];   // 16 KiB each
  __shared__ unsigned short Bs0[4096], Bs1[4096];   // 8 KiB each

  // XCD-chunked bijective swizzle: 4624 blocks = 8 XCDs x 578
  int g = blockIdx.x;
  int xcd = g & 7, gi = g >> 3;
  int wg = xcd * 578 + gi;
  const int bm = wg >> 4;              // 0..288
  const int bn = wg & 15;              // 0..15
  const long long m0 = (long long)bm * BM;
  const int n0 = bn * BN;

  const int tid = threadIdx.x;
  const int wave = tid >> 6, lane = tid & 63;
  const int l15 = lane & 15, lhi = lane >> 4;
  const int wm = (wave >> 1) * 64;     // 0,64
  const int wn2 = (wave & 1) * 32;     // 0,32

  f32x4 acc[4][2];
#pragma unroll
  for (int i = 0; i < 4; ++i)
#pragma unroll
    for (int j = 0; j < 2; ++j) acc[i][j] = (f32x4){0.f, 0.f, 0.f, 0.f};

  // staging: A rows wave*32+i*8+rl (4 gloads), B rows wave*16+i*8+rl (2)
  // swizzle: LDS[row][q] = global[row][q ^ (row&7)]; row&7 = lane>>3
  const int rowbase = wave * 32;
  const int rbB = wave * 16;
  const int rl = lane >> 3;
  const int csrc = (((lane & 7) ^ rl) << 3);   // elems

  // frag reads: desired chunk q = ks*4+lhi -> LDS chunk q ^ (l15&7)
  const int sl0 = ((lhi ^ (l15 & 7)) << 3);
  const int sl1 = sl0 ^ 32;

#define STAGE(t, As_, Bs_)                                                       \
  do { const size_t ko = (size_t)(t) * BKT;                                      \
    _Pragma("unroll")                                                            \
    for (int i = 0; i < 4; ++i) {                                                \
      int r = rowbase + i * 8;                                                   \
      GLOAD_LDS16(xbf + (size_t)(m0 + r + rl) * DDIM + ko + csrc, &As_[r * BKT]);\
    }                                                                            \
    _Pragma("unroll")                                                            \
    for (int i = 0; i < 2; ++i) {                                                \
      int r = rbB + i * 8;                                                       \
      GLOAD_LDS16(wbf + (size_t)(n0 + r + rl) * DDIM + ko + csrc, &Bs_[r * BKT]);\
    } } while (0)

#define COMPUTE(As_, Bs_)                                                        \
  do { bf16x8 af[4][2], bfv[2][2];                                               \
    _Pragma("unroll")                                                            \
    for (int nf = 0; nf < 2; ++nf) {                                             \
      bfv[nf][0] = *(const bf16x8*)&Bs_[(wn2 + nf * 16 + l15) * BKT + sl0];      \
      bfv[nf][1] = *(const bf16x8*)&Bs_[(wn2 + nf * 16 + l15) * BKT + sl1];      \
    }                                                                            \
    _Pragma("unroll")                                                            \
    for (int f = 0; f < 4; ++f) {                                                \
      af[f][0] = *(const bf16x8*)&As_[(wm + f * 16 + l15) * BKT + sl0];          \
      af[f][1] = *(const bf16x8*)&As_[(wm + f * 16 + l15) * BKT + sl1];          \
    }                                                                            \
    _Pragma("unroll")                                                            \
    for (int f = 0; f < 4; ++f)                                                  \
      _Pragma("unroll")                                                          \
      for (int nf = 0; nf < 2; ++nf)                                             \
        _Pragma("unroll")                                                        \
        for (int ks = 0; ks < 2; ++ks)                                           \
          acc[f][nf] = __builtin_amdgcn_mfma_f32_16x16x32_bf16(                  \
              af[f][ks], bfv[nf][ks], acc[f][nf], 0, 0, 0);                      \
  } while (0)

#define BAR() do { __builtin_amdgcn_s_barrier(); asm volatile("" ::: "memory"); } while (0)
#define LGKM0() asm volatile("s_waitcnt lgkmcnt(0)" ::: "memory")
#define VM6() asm volatile("s_waitcnt vmcnt(6)" ::: "memory")
#define VM0() asm volatile("s_waitcnt vmcnt(0)" ::: "memory")

  // prologue: stage tiles 0 and 1
  STAGE(0, As0, Bs0);
  STAGE(1, As1, Bs1);
  VM6();                                // tile 0 landed (mine); tile 1 in flight
  BAR();                                // everyone's tile 0 landed

  // main loop, unrolled x2 (tiles 2i, 2i+1)
#pragma unroll 1
  for (int i = 0; i < 8; ++i) {
    const int t = 2 * i;
    COMPUTE(As0, Bs0);                  // tile t
    LGKM0(); BAR();                     // all waves done reading buf0
    if (t + 2 < 16) { STAGE(t + 2, As0, Bs0); VM6(); }
    else            { VM0(); }          // drain: tile 15 landed
    BAR();                              // everyone's tile t+1 landed
    COMPUTE(As1, Bs1);                  // tile t+1
    if (t + 3 < 16) {
      LGKM0(); BAR();
      STAGE(t + 3, As1, Bs1); VM6();
      BAR();                            // everyone's tile t+2 landed
    }
  }
#undef STAGE
#undef COMPUTE

  // LoRA rank-32 extra K-steps, masked per batch (128-row tile spans <= 2)
  long long mlast = m0 + BM - 1; if (mlast > M_REAL - 1) mlast = M_REAL - 1;
  int b_lo = (int)(m0 / SSEQ);
  int b_hi = (int)(mlast / SSEQ);
  for (int bs = b_lo; bs <= b_hi; ++bs) {
    bf16x8 gb[2];
#pragma unroll
    for (int nf = 0; nf < 2; ++nf) {
      int n = n0 + wn2 + nf * 16 + l15;
      gb[nf] = *(const bf16x8*)&gbbf[((size_t)bs * 1024 + n) * 32 + lhi * 8];
    }
#pragma unroll
    for (int f = 0; f < 4; ++f) {
      long long m = m0 + wm + f * 16 + l15;
      bf16x8 v = *(const bf16x8*)&xabf[(size_t)m * 32 + lhi * 8];  // pad rows zero
      if ((int)(m / SSEQ) != bs) {
#pragma unroll
        for (int j = 0; j < 8; ++j) v[j] = 0;
      }
#pragma unroll
      for (int nf = 0; nf < 2; ++nf)
        acc[f][nf] = __builtin_amdgcn_mfma_f32_16x16x32_bf16(v, gb[nf], acc[f][nf], 0, 0, 0);
    }
  }

  // epilogue: + bias; per-wave LDS transpose (16x32 f32, stride 36, in As0);
  // NT f32x4 stores (full 128B lines). Own-region, intra-wave in-order.
  {
    float* lfs = (float*)As0 + wave * 640;   // 16*36=576 used, 640 spacing
    const long long mrow0 = m0 + wm;
    const int ncol0 = n0 + wn2;
#pragma unroll
    for (int i = 0; i < 4; ++i) {
#pragma unroll
      for (int j = 0; j < 2; ++j) {
        float bv = bias[ncol0 + j * 16 + l15];
#pragma unroll
        for (int reg = 0; reg < 4; ++reg)
          lfs[(lhi * 4 + reg) * 36 + j * 16 + l15] = acc[i][j][reg] + bv;
      }
#pragma unroll
      for (int rr = 0; rr < 2; ++rr) {
        int r16 = rr * 8 + (lane >> 3);
        f32x4 v = *(const f32x4*)&lfs[r16 * 36 + (lane & 7) * 4];
        long long m = mrow0 + i * 16 + r16;
        if (m < M_REAL)
          __builtin_nontemporal_store(v, (f32x4*)&out[m * DDIM + ncol0 + (lane & 7) * 4]);
      }
    }
  }
}

extern "C" void kernel_launch(void* const* d_in, const int* in_sizes, int n_in,
                              void* d_out, int out_size, void* d_ws, size_t ws_size,
                              hipStream_t stream) {
  const float* x      = (const float*)d_in[0];
  const int*   idx    = (const int*)d_in[1];
  const float* gates  = (const float*)d_in[2];
  const float* W      = (const float*)d_in[3];
  const float* A_all  = (const float*)d_in[4];
  const float* B_all  = (const float*)d_in[5];
  const float* bias   = (const float*)d_in[6];
  float* out = (float*)d_out;

  char* ws = (char*)d_ws;
  unsigned short* xbf  = (unsigned short*)(ws + XBF_OFF);
  unsigned short* wbf  = (unsigned short*)(ws + WBF_OFF);
  unsigned short* abf  = (unsigned short*)(ws + ABF_OFF);
  unsigned short* xabf = (unsigned short*)(ws + XABF_OFF);
  unsigned short* gbbf = (unsigned short*)(ws + GBBF_OFF);

  prep_kernel<<<dim3(872), dim3(256), 0, stream>>>(W, A_all, B_all, idx, gates,
                                                   wbf, abf, gbbf, xbf, xabf);
  cast_xa_kernel<<<dim3(640), dim3(256), 0, stream>>>(x, abf, idx, xbf, xabf);
  gemm_kernel<<<dim3(4624), dim3(256), 0, stream>>>(xbf, wbf, xabf, gbbf, bias, out);
}

// Round 19
// 153.150 us; speedup vs baseline: 1.7930x; 1.0446x over previous
//
#include <hip/hip_runtime.h>
#include <hip/hip_bf16.h>
#include <stdint.h>

// Problem constants
#define M_REAL 36928LL      // 64*577
#define M_PAD  36992LL      // 289*128
#define DDIM   1024
#define SSEQ   577
#define NBATCH 64

typedef __attribute__((ext_vector_type(8))) short bf16x8;
typedef __attribute__((ext_vector_type(4))) float f32x4;

// ws layout (bytes)
#define XBF_OFF   0ULL                  // 36992*1024*2 = 75,759,616
#define WBF_OFF   75759616ULL           // 1024*1024*2  =  2,097,152
#define ABF_OFF   77856768ULL           // 8*16*1024*2  =    262,144
#define XABF_OFF  78118912ULL           // 36992*32*2   =  2,367,488
#define GBBF_OFF  80486400ULL           // 64*1024*32*2 =  4,194,304
#define WS_NEED   84680704ULL

__device__ __forceinline__ unsigned short f2bf(float f) {
  union { float f; unsigned int u; } v; v.f = f;
  unsigned int u = v.u;
  unsigned int r = (u + 0x7fffu + ((u >> 16) & 1u)) >> 16;  // RNE
  return (unsigned short)r;
}

__device__ __forceinline__ bf16x8 cvt8(const float* __restrict__ p) {
  float4 a = *(const float4*)p;
  float4 b = *(const float4*)(p + 4);
  bf16x8 o;
  o[0] = (short)f2bf(a.x); o[1] = (short)f2bf(a.y);
  o[2] = (short)f2bf(a.z); o[3] = (short)f2bf(a.w);
  o[4] = (short)f2bf(b.x); o[5] = (short)f2bf(b.y);
  o[6] = (short)f2bf(b.z); o[7] = (short)f2bf(b.w);
  return o;
}

#define GLOAD_LDS16(gsrc, ldst)                                                  \
  __builtin_amdgcn_global_load_lds((const __attribute__((address_space(1))) void*)(gsrc), \
                                   (__attribute__((address_space(3))) void*)(ldst), 16, 0, 0)

// ---------------- kernel 1: prep (cast W, cast A, build gB, zero pads) ------
__global__ void prep_kernel(const float* __restrict__ W,
                            const float* __restrict__ A_all,
                            const float* __restrict__ B_all,
                            const int* __restrict__ idx,
                            const float* __restrict__ gates,
                            unsigned short* __restrict__ wbf,
                            unsigned short* __restrict__ abf,
                            unsigned short* __restrict__ gbbf,
                            unsigned short* __restrict__ xbf,
                            unsigned short* __restrict__ xabf) {
  const int W_UNITS = 131072;                 // 8 elems each (1M total)
  const int A_UNITS = 16384;                  // 8 elems each (131072 total)
  const int G_UNITS = 65536;                  // one (b,n) row of 32 each
  const int XP_UNITS = 8192;                  // xbf pad rows (64 rows * 1024 / 8)
  const int P_UNITS = 2048;                   // xa pad elems (64 rows * 32)
  const int TOTAL = W_UNITS + A_UNITS + G_UNITS + XP_UNITS + P_UNITS; // 223232
  int u = blockIdx.x * blockDim.x + threadIdx.x;
  int stride = gridDim.x * blockDim.x;
  for (; u < TOTAL; u += stride) {
    if (u < W_UNITS) {
      int i = u * 8;
      *(bf16x8*)(wbf + i) = cvt8(W + i);
    } else if (u < W_UNITS + A_UNITS) {
      int i = (u - W_UNITS) * 8;
      *(bf16x8*)(abf + i) = cvt8(A_all + i);
    } else if (u < W_UNITS + A_UNITS + G_UNITS) {
      int v = u - W_UNITS - A_UNITS;
      int b = v >> 10;
      int n = v & 1023;
      unsigned short tmp[32];
#pragma unroll
      for (int k = 0; k < 2; ++k) {
        int e = idx[b * 2 + k];
        float g = gates[b * 2 + k];
        const float* Br = B_all + ((size_t)e * 1024 + n) * 16;
#pragma unroll
        for (int r = 0; r < 16; ++r) tmp[k * 16 + r] = f2bf(g * Br[r]);
      }
      unsigned short* dst = gbbf + (size_t)v * 32;
#pragma unroll
      for (int j = 0; j < 32; ++j) dst[j] = tmp[j];
    } else if (u < W_UNITS + A_UNITS + G_UNITS + XP_UNITS) {
      int v = u - W_UNITS - A_UNITS - G_UNITS;
      bf16x8 z;
#pragma unroll
      for (int j = 0; j < 8; ++j) z[j] = 0;
      *(bf16x8*)(xbf + (size_t)M_REAL * DDIM + (size_t)v * 8) = z;
    } else {
      int v = u - W_UNITS - A_UNITS - G_UNITS - XP_UNITS;
      xabf[(size_t)M_REAL * 32 + v] = 0;
    }
  }
}

// ---------------- kernel 2: fused cast x->bf16 + xa = x @ A_sel^T -----------
// ~6.6 TB/s (HBM roofline), do not touch.
__global__ __launch_bounds__(256) void cast_xa_kernel(
    const float* __restrict__ x,
    const unsigned short* __restrict__ abf,
    const int* __restrict__ idx,
    unsigned short* __restrict__ xbf,
    unsigned short* __restrict__ xabf) {
  int bid = blockIdx.x;
  int b = bid / 10;
  int s0 = (bid % 10) * 64;
  int wave = threadIdx.x >> 6;
  int lane = threadIdx.x & 63;
  int l15 = lane & 15, lhi = lane >> 4;

  int srow = s0 + wave * 16 + l15;
  bool valid = srow < SSEQ;
  long long mrow = (long long)b * SSEQ + (valid ? srow : 0);
  const float* xrow = x + (size_t)mrow * DDIM;
  unsigned short* xbrow = xbf + (size_t)mrow * DDIM;
  int e0 = idx[b * 2 + 0], e1 = idx[b * 2 + 1];
  const unsigned short* ar0 = abf + ((size_t)e0 * 16 + l15) * DDIM;
  const unsigned short* ar1 = abf + ((size_t)e1 * 16 + l15) * DDIM;

  f32x4 acc0 = {0.f, 0.f, 0.f, 0.f}, acc1 = {0.f, 0.f, 0.f, 0.f};
  for (int k = 0; k < DDIM; k += 32) {
    int ko = k + lhi * 8;
    bf16x8 a;
    if (valid) {
      a = cvt8(xrow + ko);
      *(bf16x8*)(xbrow + ko) = a;
    } else {
#pragma unroll
      for (int j = 0; j < 8; ++j) a[j] = 0;
    }
    bf16x8 b0 = *(const bf16x8*)(ar0 + ko);
    bf16x8 b1 = *(const bf16x8*)(ar1 + ko);
    acc0 = __builtin_amdgcn_mfma_f32_16x16x32_bf16(a, b0, acc0, 0, 0, 0);
    acc1 = __builtin_amdgcn_mfma_f32_16x16x32_bf16(a, b1, acc1, 0, 0, 0);
  }
  // C layout: col = lane&15 (=r), row = (lane>>4)*4+reg
  int sout = s0 + wave * 16 + lhi * 4;
#pragma unroll
  for (int reg = 0; reg < 4; ++reg) {
    int s = sout + reg;
    if (s < SSEQ) {
      size_t mo = ((size_t)b * SSEQ + s) * 32;
      xabf[mo + l15]      = f2bf(acc0[reg]);
      xabf[mo + 16 + l15] = f2bf(acc1[reg]);
    }
  }
}

// ---------------- kernel 3: 128x128 GEMM, LDS dbuf + counted vmcnt ----------
// C[m,n] = sum_d x[m,d]*W[n,d] + bias[n] + sum_kr xa[m,kr]*gB[b(m),n,kr]
// r18's pipeline (counted vmcnt, raw barriers) at the 128x128 tile:
// wave tile 64x64 -> 32 FLOP/LDS-byte (1.5x r18) since LDS was 68% busy.
// 64KB LDS -> 2 blocks/CU; pipeline supplies latency hiding (r18 evidence).
// Ledger: STAGE = 8 loads/thread; vmcnt(8) after STAGE(t+2) proves t+1 landed;
// lgkm0+barrier before overwrite proves all waves done reading.
#define BM 128
#define BN 128
#define BKT 64
__global__ __launch_bounds__(256, 2) void gemm_kernel(
    const unsigned short* __restrict__ xbf,
    const unsigned short* __restrict__ wbf,
    const unsigned short* __restrict__ xabf,
    const unsigned short* __restrict__ gbbf,
    const float* __restrict__ bias,
    float* __restrict__ out) {
  __shared__ unsigned short As0[8192], As1[8192];   // 16 KiB each
  __shared__ unsigned short Bs0[8192], Bs1[8192];   // 16 KiB each

  // XCD-chunked bijective swizzle: 2312 blocks = 8 XCDs x 289
  int g = blockIdx.x;
  int xcd = g & 7, gi = g >> 3;
  int wg = xcd * 289 + gi;
  const int bm = wg >> 3;              // 0..288
  const int bn = wg & 7;               // 0..7
  const long long m0 = (long long)bm * BM;
  const int n0 = bn * BN;

  const int tid = threadIdx.x;
  const int wave = tid >> 6, lane = tid & 63;
  const int l15 = lane & 15, lhi = lane >> 4;
  const int wm = (wave >> 1) * 64, wn = (wave & 1) * 64;

  f32x4 acc[4][4];
#pragma unroll
  for (int i = 0; i < 4; ++i)
#pragma unroll
    for (int j = 0; j < 4; ++j) acc[i][j] = (f32x4){0.f, 0.f, 0.f, 0.f};

  // staging: wave stages 32 rows of A and 32 of B; row = wave*32+i*8+rl
  // swizzle: LDS[row][q] = global[row][q ^ (row&7)]; row&7 = lane>>3
  const int rowbase = wave * 32;
  const int rl = lane >> 3;
  const int csrc = (((lane & 7) ^ rl) << 3);   // elems

  // frag reads: desired chunk q = ks*4+lhi -> LDS chunk q ^ (l15&7)
  const int sl0 = ((lhi ^ (l15 & 7)) << 3);
  const int sl1 = sl0 ^ 32;

#define STAGE(t, As_, Bs_)                                                       \
  do { const size_t ko = (size_t)(t) * BKT;                                      \
    _Pragma("unroll")                                                            \
    for (int i = 0; i < 4; ++i) {                                                \
      int r = rowbase + i * 8;                                                   \
      GLOAD_LDS16(xbf + (size_t)(m0 + r + rl) * DDIM + ko + csrc, &As_[r * BKT]);\
    }                                                                            \
    _Pragma("unroll")                                                            \
    for (int i = 0; i < 4; ++i) {                                                \
      int r = rowbase + i * 8;                                                   \
      GLOAD_LDS16(wbf + (size_t)(n0 + r + rl) * DDIM + ko + csrc, &Bs_[r * BKT]);\
    } } while (0)

#define COMPUTE(As_, Bs_)                                                        \
  do { bf16x8 af[4][2], bfv[4][2];                                               \
    _Pragma("unroll")                                                            \
    for (int f = 0; f < 4; ++f) {                                                \
      af[f][0]  = *(const bf16x8*)&As_[(wm + f * 16 + l15) * BKT + sl0];         \
      af[f][1]  = *(const bf16x8*)&As_[(wm + f * 16 + l15) * BKT + sl1];         \
      bfv[f][0] = *(const bf16x8*)&Bs_[(wn + f * 16 + l15) * BKT + sl0];         \
      bfv[f][1] = *(const bf16x8*)&Bs_[(wn + f * 16 + l15) * BKT + sl1];         \
    }                                                                            \
    _Pragma("unroll")                                                            \
    for (int i = 0; i < 4; ++i)                                                  \
      _Pragma("unroll")                                                          \
      for (int j = 0; j < 4; ++j)                                                \
        _Pragma("unroll")                                                        \
        for (int ks = 0; ks < 2; ++ks)                                           \
          acc[i][j] = __builtin_amdgcn_mfma_f32_16x16x32_bf16(                   \
              af[i][ks], bfv[j][ks], acc[i][j], 0, 0, 0);                        \
  } while (0)

#define BAR() do { __builtin_amdgcn_s_barrier(); asm volatile("" ::: "memory"); } while (0)
#define LGKM0() asm volatile("s_waitcnt lgkmcnt(0)" ::: "memory")
#define VM8() asm volatile("s_waitcnt vmcnt(8)" ::: "memory")
#define VM0() asm volatile("s_waitcnt vmcnt(0)" ::: "memory")

  // prologue: stage tiles 0 and 1
  STAGE(0, As0, Bs0);
  STAGE(1, As1, Bs1);
  VM8();                                // tile 0 landed (mine); tile 1 in flight
  BAR();                                // everyone's tile 0 landed

  // main loop, unrolled x2 (tiles 2i, 2i+1)
#pragma unroll 1
  for (int i = 0; i < 8; ++i) {
    const int t = 2 * i;
    COMPUTE(As0, Bs0);                  // tile t
    LGKM0(); BAR();                     // all waves done reading buf0
    if (t + 2 < 16) { STAGE(t + 2, As0, Bs0); VM8(); }
    else            { VM0(); }          // drain: tile 15 landed
    BAR();                              // everyone's tile t+1 landed
    COMPUTE(As1, Bs1);                  // tile t+1
    if (t + 3 < 16) {
      LGKM0(); BAR();
      STAGE(t + 3, As1, Bs1); VM8();
      BAR();                            // everyone's tile t+2 landed
    }
  }
#undef STAGE
#undef COMPUTE

  // LoRA rank-32 extra K-steps, masked per batch (128-row tile spans <= 2)
  long long mlast = m0 + BM - 1; if (mlast > M_REAL - 1) mlast = M_REAL - 1;
  int b_lo = (int)(m0 / SSEQ);
  int b_hi = (int)(mlast / SSEQ);
  for (int bs = b_lo; bs <= b_hi; ++bs) {
    bf16x8 af[4], bfv[4];
#pragma unroll
    for (int f = 0; f < 4; ++f) {
      long long m = m0 + wm + f * 16 + l15;
      bf16x8 v = *(const bf16x8*)&xabf[(size_t)m * 32 + lhi * 8];  // pad rows zero
      if ((int)(m / SSEQ) != bs) {
#pragma unroll
        for (int j = 0; j < 8; ++j) v[j] = 0;
      }
      af[f] = v;
      int n = n0 + wn + f * 16 + l15;
      bfv[f] = *(const bf16x8*)&gbbf[((size_t)bs * 1024 + n) * 32 + lhi * 8];
    }
#pragma unroll
    for (int i = 0; i < 4; ++i)
#pragma unroll
      for (int j = 0; j < 4; ++j)
        acc[i][j] = __builtin_amdgcn_mfma_f32_16x16x32_bf16(af[i], bfv[j], acc[i][j], 0, 0, 0);
  }

  // epilogue: + bias; per-wave LDS transpose (stride 68 f32, 16B-aligned);
  // NT f32x4 stores (full 128B lines). r13-validated layout: waves 0-1 in
  // As0 (last read: tile 14, barrier-protected), waves 2-3 in Bs0.
  {
    float* lfs = (float*)(wave < 2 ? (void*)As0 : (void*)Bs0);
    const int ebase = (wave & 1) * 1104;     // 16*68=1088 used, +16 spacing
    const long long mrow0 = m0 + wm;
    const int ncol0 = n0 + wn;
#pragma unroll
    for (int i = 0; i < 4; ++i) {
#pragma unroll
      for (int j = 0; j < 4; ++j) {
        float bv = bias[ncol0 + j * 16 + l15];
#pragma unroll
        for (int reg = 0; reg < 4; ++reg)
          lfs[ebase + (lhi * 4 + reg) * 68 + j * 16 + l15] = acc[i][j][reg] + bv;
      }
      // intra-wave LDS in-order; compiler inserts lgkmcnt before reads
#pragma unroll
      for (int rr = 0; rr < 4; ++rr) {
        int row = rr * 4 + lhi;
        f32x4 v = *(const f32x4*)&lfs[ebase + row * 68 + l15 * 4];
        long long m = mrow0 + i * 16 + row;
        if (m < M_REAL)
          __builtin_nontemporal_store(v, (f32x4*)&out[m * DDIM + ncol0 + l15 * 4]);
      }
    }
  }
}

extern "C" void kernel_launch(void* const* d_in, const int* in_sizes, int n_in,
                              void* d_out, int out_size, void* d_ws, size_t ws_size,
                              hipStream_t stream) {
  const float* x      = (const float*)d_in[0];
  const int*   idx    = (const int*)d_in[1];
  const float* gates  = (const float*)d_in[2];
  const float* W      = (const float*)d_in[3];
  const float* A_all  = (const float*)d_in[4];
  const float* B_all  = (const float*)d_in[5];
  const float* bias   = (const float*)d_in[6];
  float* out = (float*)d_out;

  char* ws = (char*)d_ws;
  unsigned short* xbf  = (unsigned short*)(ws + XBF_OFF);
  unsigned short* wbf  = (unsigned short*)(ws + WBF_OFF);
  unsigned short* abf  = (unsigned short*)(ws + ABF_OFF);
  unsigned short* xabf = (unsigned short*)(ws + XABF_OFF);
  unsigned short* gbbf = (unsigned short*)(ws + GBBF_OFF);

  prep_kernel<<<dim3(872), dim3(256), 0, stream>>>(W, A_all, B_all, idx, gates,
                                                   wbf, abf, gbbf, xbf, xabf);
  cast_xa_kernel<<<dim3(640), dim3(256), 0, stream>>>(x, abf, idx, xbf, xabf);
  gemm_kernel<<<dim3(2312), dim3(256), 0, stream>>>(xbf, wbf, xabf, gbbf, bias, out);
}